// Round 5
// baseline (96.423 us; speedup 1.0000x reference)
//
#include <hip/hip_runtime.h>

// Problem constants (fixed by the reference):
//   expert_outputs: [E=8, C=8192, D=1024] f32
//   weights:        [E, C] f32
//   token_indices:  [E, C] int32 (harness converts integer inputs to int32)
//   out:            [B=8, S=4096, D=1024] f32  (flat: 32768 x 1024)
#define E_EXP 8
#define C_CAP 8192
#define D_DIM 1024
#define N_ROWS (E_EXP * C_CAP)      // 65536  (row ids fit in ushort: max 65535)
#define N_TOK  (8 * 4096)           // 32768
#define TPB    32                   // tokens owned per block
#define NBLK   (N_TOK / TPB)        // 1024 blocks, all co-resident (4/CU)
#define SLOTS_K 16                  // slots per token (Poisson(2): P(>16) ~ 1e-12)

typedef float f32x4 __attribute__((ext_vector_type(4)));

__device__ __forceinline__ f32x4 ntload4(const float* p) {
    return __builtin_nontemporal_load(reinterpret_cast<const f32x4*>(p));
}

// Compile-time-N gather: all weight loads and all row loads issue
// back-to-back (static indexing -> registers, max MLP), then FMA.
template<int N>
__device__ __forceinline__ f32x4 gather_fixed(const float* __restrict__ eo,
                                              const float* __restrict__ w,
                                              const unsigned short* id, int t)
{
    int row[N];
    #pragma unroll
    for (int r = 0; r < N; ++r) row[r] = id[r];          // LDS broadcast reads
    float wt[N];
    #pragma unroll
    for (int r = 0; r < N; ++r) wt[r] = w[row[r]];       // independent loads
    f32x4 v[N];
    #pragma unroll
    for (int r = 0; r < N; ++r)
        v[r] = ntload4(eo + (size_t)row[r] * D_DIM + t * 4);  // independent loads
    f32x4 acc = wt[0] * v[0];
    #pragma unroll
    for (int r = 1; r < N; ++r) acc += wt[r] * v[r];
    return acc;
}

// One kernel, one dispatch. Each block owns TPB consecutive tokens:
//   phase 1: scan all 64K token indices (L2-broadcast), collect own rows in LDS
//   phase 2: per token, gather <=SLOTS_K rows with specialized MLP paths,
//            one nontemporal float4 store (doubles as output init).
__global__ __launch_bounds__(256) void combine_fused(
    const float* __restrict__ expert_outputs,
    const float* __restrict__ weights,
    const int* __restrict__ token_indices,
    float* __restrict__ out)
{
    __shared__ int cnt[TPB];
    __shared__ unsigned short sl[TPB][SLOTS_K];

    const int t = threadIdx.x;
    const int tok0 = blockIdx.x * TPB;

    if (t < TPB) cnt[t] = 0;
    __syncthreads();

    // ---- Phase 1: scan. 64 iters x 256 threads x int4 = 65536 indices. ----
    const int4* ti4 = reinterpret_cast<const int4*>(token_indices);
    #pragma unroll 4
    for (int i = 0; i < N_ROWS / 4 / 256; ++i) {
        const int idx = i * 256 + t;                 // int4 index (coalesced)
        const int4 v = ti4[idx];
        const int rowb = idx * 4;
        unsigned d;
        d = (unsigned)(v.x - tok0); if (d < TPB) { int s = atomicAdd(&cnt[d], 1); if (s < SLOTS_K) sl[d][s] = (unsigned short)(rowb + 0); }
        d = (unsigned)(v.y - tok0); if (d < TPB) { int s = atomicAdd(&cnt[d], 1); if (s < SLOTS_K) sl[d][s] = (unsigned short)(rowb + 1); }
        d = (unsigned)(v.z - tok0); if (d < TPB) { int s = atomicAdd(&cnt[d], 1); if (s < SLOTS_K) sl[d][s] = (unsigned short)(rowb + 2); }
        d = (unsigned)(v.w - tok0); if (d < TPB) { int s = atomicAdd(&cnt[d], 1); if (s < SLOTS_K) sl[d][s] = (unsigned short)(rowb + 3); }
    }
    __syncthreads();

    // ---- Phase 2: gather own tokens. ----
    for (int j = 0; j < TPB; ++j) {
        const int n = cnt[j];
        f32x4 acc = {0.f, 0.f, 0.f, 0.f};
        if (__builtin_expect(n <= SLOTS_K, 1)) {
            switch (n) {
            case 0: break;
            case 1: acc = gather_fixed<1>(expert_outputs, weights, sl[j], t); break;
            case 2: acc = gather_fixed<2>(expert_outputs, weights, sl[j], t); break;
            case 3: acc = gather_fixed<3>(expert_outputs, weights, sl[j], t); break;
            case 4: acc = gather_fixed<4>(expert_outputs, weights, sl[j], t); break;
            default: {
                int r = 0;
                for (; r + 4 <= n; r += 4)
                    acc += gather_fixed<4>(expert_outputs, weights, &sl[j][r], t);
                for (; r < n; ++r) {
                    const int row = sl[j][r];
                    acc += weights[row] *
                           ntload4(expert_outputs + (size_t)row * D_DIM + t * 4);
                }
            } }
        } else {
            // Exact rare path (n > SLOTS_K: impossible for this distribution):
            // rescan global indices for this token only.
            const int tok = tok0 + j;
            for (int row = 0; row < N_ROWS; ++row) {
                if (token_indices[row] == tok) {
                    acc += weights[row] *
                           ntload4(expert_outputs + (size_t)row * D_DIM + t * 4);
                }
            }
        }
        // Zero rows included -> output fully initialized, poison-safe.
        __builtin_nontemporal_store(acc,
            reinterpret_cast<f32x4*>(out + (size_t)(tok0 + j) * D_DIM) + t);
    }
}

extern "C" void kernel_launch(void* const* d_in, const int* in_sizes, int n_in,
                              void* d_out, int out_size, void* d_ws, size_t ws_size,
                              hipStream_t stream) {
    const float* expert_outputs = (const float*)d_in[0];
    const float* weights        = (const float*)d_in[1];
    const int*   token_indices  = (const int*)d_in[2];
    float* out = (float*)d_out;

    combine_fused<<<NBLK, 256, 0, stream>>>(
        expert_outputs, weights, token_indices, out);
}

// Round 6
// 88.367 us; speedup vs baseline: 1.0912x; 1.0912x over previous
//
#include <hip/hip_runtime.h>

// Problem constants (fixed by the reference):
//   expert_outputs: [E=8, C=8192, D=1024] f32
//   weights:        [E, C] f32
//   token_indices:  [E, C] int32 (harness converts integer inputs to int32)
//   out:            [B=8, S=4096, D=1024] f32  (flat: 32768 x 1024)
#define E_EXP 8
#define C_CAP 8192
#define D_DIM 1024
#define N_ROWS (E_EXP * C_CAP)      // 65536  (row ids fit in ushort)
#define N_TOK  (8 * 4096)           // 32768
#define SLOTS_K 16                  // slots per token (Poisson(2): P(>16) ~ 1e-12)
#define WPB 4                       // waves (=tokens) per block
#define GATHER_BLOCKS (N_TOK / WPB) // 8192

typedef float f32x4 __attribute__((ext_vector_type(4)));

__device__ __forceinline__ f32x4 ntload4(const float* p) {
    return __builtin_nontemporal_load(reinterpret_cast<const f32x4*>(p));
}

// ---------------- Pass 1: build inverse index (token -> row list) ----------
__global__ __launch_bounds__(256) void combine_build(
    const int* __restrict__ token_indices,
    int* __restrict__ count,            // [N_TOK], pre-zeroed
    unsigned short* __restrict__ slots) // [N_TOK * SLOTS_K]
{
    const int row = blockIdx.x * 256 + threadIdx.x;   // 0 .. N_ROWS-1
    const int tok = token_indices[row];
    const int slot = atomicAdd(&count[tok], 1);
    if (slot < SLOTS_K) {
        slots[(size_t)tok * SLOTS_K + slot] = (unsigned short)row;
    }
    // Tokens exceeding SLOTS_K rows take the exact rescan path in gather.
}

// Gather N rows into 4 chunk-accumulators. All 4*N row loads are
// independent and issue back-to-back (static indexing -> registers).
template<int N>
__device__ __forceinline__ void gather_rows(const float* __restrict__ eo,
                                            const float* __restrict__ w,
                                            const unsigned short* __restrict__ id,
                                            int lane, f32x4 acc[4])
{
    int row[N];
    #pragma unroll
    for (int r = 0; r < N; ++r) row[r] = id[r];
    float wt[N];
    #pragma unroll
    for (int r = 0; r < N; ++r) wt[r] = w[row[r]];
    f32x4 v[N][4];
    #pragma unroll
    for (int r = 0; r < N; ++r) {
        const float* base = eo + (size_t)row[r] * D_DIM + lane * 4;
        #pragma unroll
        for (int c = 0; c < 4; ++c)
            v[r][c] = ntload4(base + c * 256);        // 4 indep 1KB-wide loads
    }
    #pragma unroll
    for (int r = 0; r < N; ++r) {
        #pragma unroll
        for (int c = 0; c < 4; ++c) acc[c] += wt[r] * v[r][c];
    }
}

// ---------------- Pass 2: one WAVE per token, no output atomics ------------
__global__ __launch_bounds__(256) void combine_gather(
    const float* __restrict__ expert_outputs,
    const float* __restrict__ weights,
    const int* __restrict__ token_indices,
    const int* __restrict__ count,
    const unsigned short* __restrict__ slots,
    float* __restrict__ out)
{
    const int wv   = threadIdx.x >> 6;                // 0..3
    const int lane = threadIdx.x & 63;
    const int tok  = blockIdx.x * WPB + wv;           // 0 .. N_TOK-1

    const int n = count[tok];                         // wave-uniform (L2)
    const unsigned short* sl = slots + (size_t)tok * SLOTS_K;

    f32x4 acc[4];
    #pragma unroll
    for (int c = 0; c < 4; ++c) acc[c] = (f32x4)(0.f);

    if (__builtin_expect(n <= SLOTS_K, 1)) {
        switch (n) {
        case 0: break;
        case 1: gather_rows<1>(expert_outputs, weights, sl, lane, acc); break;
        case 2: gather_rows<2>(expert_outputs, weights, sl, lane, acc); break;
        case 3: gather_rows<3>(expert_outputs, weights, sl, lane, acc); break;
        default: {
            int r = 0;
            for (; r + 2 <= n; r += 2)
                gather_rows<2>(expert_outputs, weights, sl + r, lane, acc);
            if (r < n)
                gather_rows<1>(expert_outputs, weights, sl + r, lane, acc);
        } }
    } else {
        // Exact rare path (n > SLOTS_K: ~impossible for this distribution).
        for (int row = 0; row < N_ROWS; ++row) {
            if (token_indices[row] == tok) {
                const float w = weights[row];
                const float* base = expert_outputs + (size_t)row * D_DIM + lane * 4;
                #pragma unroll
                for (int c = 0; c < 4; ++c) acc[c] += w * ntload4(base + c * 256);
            }
        }
    }

    // Zero tokens included -> output fully initialized, poison-safe.
    float* ob = out + (size_t)tok * D_DIM + lane * 4;
    #pragma unroll
    for (int c = 0; c < 4; ++c)
        __builtin_nontemporal_store(acc[c], reinterpret_cast<f32x4*>(ob + c * 256));
}

extern "C" void kernel_launch(void* const* d_in, const int* in_sizes, int n_in,
                              void* d_out, int out_size, void* d_ws, size_t ws_size,
                              hipStream_t stream) {
    const float* expert_outputs = (const float*)d_in[0];
    const float* weights        = (const float*)d_in[1];
    const int*   token_indices  = (const int*)d_in[2];
    float* out = (float*)d_out;

    // Workspace layout:
    //   count : N_TOK int            (128 KB)
    //   slots : N_TOK*SLOTS_K ushort (1 MB)
    int* count = (int*)d_ws;
    unsigned short* slots = (unsigned short*)(count + N_TOK);

    // Zero the counters every call (deterministic across graph replays).
    hipMemsetAsync(count, 0, (size_t)N_TOK * sizeof(int), stream);

    combine_build<<<N_ROWS / 256, 256, 0, stream>>>(
        token_indices, count, slots);

    combine_gather<<<GATHER_BLOCKS, 256, 0, stream>>>(
        expert_outputs, weights, token_indices, count, slots, out);
}

// Round 8
// 74.440 us; speedup vs baseline: 1.2953x; 1.1871x over previous
//
#include <hip/hip_runtime.h>

// Problem constants (fixed by the reference):
//   expert_outputs: [E=8, C=8192, D=1024] f32
//   weights:        [E, C] f32
//   token_indices:  [E, C] int32 (harness converts integer inputs to int32)
//   out:            [B=8, S=4096, D=1024] f32  (flat: 32768 x 1024)
#define E_EXP 8
#define C_CAP 8192
#define D_DIM 1024
#define N_ROWS (E_EXP * C_CAP)      // 65536  (row ids fit in ushort)
#define N_TOK  (8 * 4096)           // 32768
#define SLOTS_K 16                  // slots per token (Poisson(2): P(>16) ~ 1e-12)
#define WPB 4                       // waves (=tokens) per block
#define GATHER_BLOCKS (N_TOK / WPB) // 8192

typedef float f32x4 __attribute__((ext_vector_type(4)));

// Plain cached load for the expert rows: the 256 MB input is ~L3-resident
// across graph replays (round-2 counters: FETCH 135 MB << 256 MB input).
// NT loads would mark it evict-first and forfeit that reuse.
__device__ __forceinline__ f32x4 ld4(const float* p) {
    return *reinterpret_cast<const f32x4*>(p);
}

// ---------------- Pass 1: build inverse index (token -> row list) ----------
__global__ __launch_bounds__(256) void combine_build(
    const int* __restrict__ token_indices,
    int* __restrict__ count,            // [N_TOK], pre-zeroed
    unsigned short* __restrict__ slots) // [N_TOK * SLOTS_K]
{
    const int row = blockIdx.x * 256 + threadIdx.x;   // 0 .. N_ROWS-1
    const int tok = token_indices[row];
    const int slot = atomicAdd(&count[tok], 1);
    if (slot < SLOTS_K) {
        slots[(size_t)tok * SLOTS_K + slot] = (unsigned short)row;
    }
    // Tokens exceeding SLOTS_K rows take the exact rescan path in gather.
}

// Gather N rows into 4 chunk-accumulators. All 4*N row loads are
// independent and issue back-to-back (static indexing -> registers).
template<int N>
__device__ __forceinline__ void gather_rows(const float* __restrict__ eo,
                                            const float* __restrict__ w,
                                            const unsigned short* __restrict__ id,
                                            int lane, f32x4 acc[4])
{
    int row[N];
    #pragma unroll
    for (int r = 0; r < N; ++r) row[r] = id[r];
    float wt[N];
    #pragma unroll
    for (int r = 0; r < N; ++r) wt[r] = w[row[r]];
    f32x4 v[N][4];
    #pragma unroll
    for (int r = 0; r < N; ++r) {
        const float* base = eo + (size_t)row[r] * D_DIM + lane * 4;
        #pragma unroll
        for (int c = 0; c < 4; ++c)
            v[r][c] = ld4(base + c * 256);            // 4 indep 1KB-wide loads
    }
    #pragma unroll
    for (int r = 0; r < N; ++r) {
        #pragma unroll
        for (int c = 0; c < 4; ++c) acc[c] += wt[r] * v[r][c];
    }
}

// ---------------- Pass 2: one WAVE per token, no output atomics ------------
__global__ __launch_bounds__(256) void combine_gather(
    const float* __restrict__ expert_outputs,
    const float* __restrict__ weights,
    const int* __restrict__ token_indices,
    const int* __restrict__ count,
    const unsigned short* __restrict__ slots,
    float* __restrict__ out)
{
    const int wv   = threadIdx.x >> 6;                // 0..3
    const int lane = threadIdx.x & 63;
    const int tok  = blockIdx.x * WPB + wv;           // 0 .. N_TOK-1

    const int n = count[tok];                         // wave-uniform (L2)
    const unsigned short* sl = slots + (size_t)tok * SLOTS_K;

    f32x4 acc[4];
    #pragma unroll
    for (int c = 0; c < 4; ++c) acc[c] = (f32x4)(0.f);

    if (__builtin_expect(n <= SLOTS_K, 1)) {
        switch (n) {
        case 0: break;
        case 1: gather_rows<1>(expert_outputs, weights, sl, lane, acc); break;
        case 2: gather_rows<2>(expert_outputs, weights, sl, lane, acc); break;
        case 3: gather_rows<3>(expert_outputs, weights, sl, lane, acc); break;
        default: {
            int r = 0;
            for (; r + 2 <= n; r += 2)
                gather_rows<2>(expert_outputs, weights, sl + r, lane, acc);
            if (r < n)
                gather_rows<1>(expert_outputs, weights, sl + r, lane, acc);
        } }
    } else {
        // Exact rare path (n > SLOTS_K: ~impossible for this distribution).
        for (int row = 0; row < N_ROWS; ++row) {
            if (token_indices[row] == tok) {
                const float w = weights[row];
                const float* base = expert_outputs + (size_t)row * D_DIM + lane * 4;
                #pragma unroll
                for (int c = 0; c < 4; ++c) acc[c] += w * ld4(base + c * 256);
            }
        }
    }

    // NT store: output is write-once — keep it from evicting the (reused)
    // input out of L2/L3. Zero tokens included -> poison-safe init.
    float* ob = out + (size_t)tok * D_DIM + lane * 4;
    #pragma unroll
    for (int c = 0; c < 4; ++c)
        __builtin_nontemporal_store(acc[c], reinterpret_cast<f32x4*>(ob + c * 256));
}

extern "C" void kernel_launch(void* const* d_in, const int* in_sizes, int n_in,
                              void* d_out, int out_size, void* d_ws, size_t ws_size,
                              hipStream_t stream) {
    const float* expert_outputs = (const float*)d_in[0];
    const float* weights        = (const float*)d_in[1];
    const int*   token_indices  = (const int*)d_in[2];
    float* out = (float*)d_out;

    // Workspace layout:
    //   count : N_TOK int            (128 KB)
    //   slots : N_TOK*SLOTS_K ushort (1 MB)
    int* count = (int*)d_ws;
    unsigned short* slots = (unsigned short*)(count + N_TOK);

    // Zero the counters every call (deterministic across graph replays).
    hipMemsetAsync(count, 0, (size_t)N_TOK * sizeof(int), stream);

    combine_build<<<N_ROWS / 256, 256, 0, stream>>>(
        token_indices, count, slots);

    combine_gather<<<GATHER_BLOCKS, 256, 0, stream>>>(
        expert_outputs, weights, token_indices, count, slots, out);
}